// Round 9
// baseline (318.383 us; speedup 1.0000x reference)
//
#include <hip/hip_runtime.h>
#include <hip/hip_bf16.h>
#include <math.h>

typedef __bf16 bf16;
typedef unsigned short u16;
typedef unsigned int u32;
typedef unsigned long long u64;
typedef long long i64;
typedef unsigned char u8;
typedef __attribute__((ext_vector_type(16))) float f32x16;
typedef __attribute__((ext_vector_type(8))) int i32x8;
typedef __attribute__((address_space(1))) void gvoid;
typedef __attribute__((address_space(3))) void svoid;

#define ENT_N 100000
#define REL_N 2000
#define ENT_CH 120        // partial chunks per qt (ent)
#define REL_CH 4          // partial chunks per (side,qt) (rel)

#define NPREPM 1536       // prep matmul blocks (128 rowgroups x 12 j-tiles)
#define NITEMS 6380       // conv items (1595 rowgroups x 4 e-chunks)
#define NCOPY  256        // passthrough copy blocks
#define NBLK   512        // flash grid (2 blocks/CU x 256 CU, co-resident)

static __device__ __forceinline__ i32x8 mk8(uint4 a, uint4 b) {
    i32x8 r;
    r[0] = (int)a.x; r[1] = (int)a.y; r[2] = (int)a.z; r[3] = (int)a.w;
    r[4] = (int)b.x; r[5] = (int)b.y; r[6] = (int)b.z; r[7] = (int)b.w;
    return r;
}

// ---------------------------------------------------------------------------
// Software grid barrier (R7-proven on this chip: 512 blocks, 2/CU, correct
// absmax). atomicAdd is device-scope on gfx950; __threadfence gives
// cross-XCD release/acquire. cnt zeroed by a hipMemsetAsync node (capturable).
// ---------------------------------------------------------------------------
static __device__ __forceinline__ void grid_barrier(u32* cnt) {
    __syncthreads();
    if (threadIdx.x == 0) {
        __threadfence();
        atomicAdd(cnt, 1u);
        while (atomicAdd(cnt, 0u) < (u32)NBLK)
            __builtin_amdgcn_s_sleep(2);
        __threadfence();
    }
    __syncthreads();
}

// ---------------------------------------------------------------------------
// prep projection tile (pipelined, verified R4): 64 out cols x 4 q-rows,
// W staged via 2-buffer LDS ping-pong, one barrier per 32-k chunk.
// ---------------------------------------------------------------------------
template<int KLEN>
static __device__ __forceinline__ void prep_tile(
    const float* __restrict__ query, const float* __restrict__ W,
    const float* __restrict__ bias, int b0, int rowbase, int qwoff,
    bf16* __restrict__ outBf, u8* __restrict__ out8, float* smem)
{
    const int t = threadIdx.x;
    float* qs = smem;               // [4][KLEN]
    float* Wl = smem + 4 * KLEN;    // 2 x [64][33]

#pragma unroll
    for (int i = 0; i < 4 * KLEN / 256; ++i) {
        const int l = t + 256 * i;
        const int r = l / KLEN, k = l % KLEN;
        qs[l] = query[(size_t)(b0 + r) * 768 + qwoff + k];
    }

    const int j = t & 63, r = t >> 6;
    const int srow = t >> 3, skq = t & 7;
    const float* wbase = W + (size_t)rowbase * KLEN;

    float4 v0, v1;
    auto wload = [&](int c) {
        v0 = *(const float4*)(wbase + (size_t)srow * KLEN + c * 32 + skq * 4);
        v1 = *(const float4*)(wbase + (size_t)(srow + 32) * KLEN + c * 32 + skq * 4);
    };
    auto wstore = [&](float* dst) {
        float* d0 = dst + srow * 33 + skq * 4;
        d0[0] = v0.x; d0[1] = v0.y; d0[2] = v0.z; d0[3] = v0.w;
        float* d1 = dst + (srow + 32) * 33 + skq * 4;
        d1[0] = v1.x; d1[1] = v1.y; d1[2] = v1.z; d1[3] = v1.w;
    };

    float acc = 0.f;
    wload(0);
    wstore(Wl);
    constexpr int NC = KLEN / 32;
    for (int c = 0; c < NC; ++c) {
        if (c + 1 < NC) wload(c + 1);
        __syncthreads();
        const float* wr = Wl + (c & 1) * 2112 + j * 33;
        const float* qr = qs + r * KLEN + c * 32;
#pragma unroll
        for (int k = 0; k < 32; ++k) acc += wr[k] * qr[k];
        if (c + 1 < NC) wstore(Wl + ((c + 1) & 1) * 2112);
    }
    acc += bias[rowbase + j];

    const size_t o = (size_t)(b0 + r) * 256 + rowbase + j;
    outBf[o] = (bf16)acc;
    out8[o] = (u8)__builtin_amdgcn_cvt_pk_fp8_f32(acc, acc, 0, false);
}

// ---------------------------------------------------------------------------
// prep_conv (R4 verbatim — best measured variant, 65.5 us):
//   blocks [0, NPREPM)             : projection tiles (pipelined)
//   blocks [NPREPM, NPREPM+nconv)  : conv items one-per-block (fatter
//                                    variants measured WORSE: R3/R8)
//   blocks [NPREPM+nconv, +NCOPY)  : passthrough copies
// ---------------------------------------------------------------------------
__global__ __launch_bounds__(256) void prep_conv(
    const float* __restrict__ query,
    const float* __restrict__ W_left, const float* __restrict__ b_left,
    const float* __restrict__ W_right, const float* __restrict__ b_right,
    const float* __restrict__ W_ent, const float* __restrict__ b_ent,
    const float* __restrict__ lc, const float* __restrict__ rc,
    bf16* __restrict__ qe, bf16* __restrict__ ql, bf16* __restrict__ qr,
    u8* __restrict__ qe8, u8* __restrict__ ql8, u8* __restrict__ qr8,
    float* __restrict__ out,
    const float* __restrict__ entF, const float* __restrict__ relF,
    u8* __restrict__ entT, u8* __restrict__ entB,
    u8* __restrict__ relT, u8* __restrict__ relB,
    int nconv)
{
    __shared__ float smem[7296];    // prep: 3072+4224; conv tile: 4160
    const int blk = blockIdx.x;
    const int t = threadIdx.x;

    if (blk < NPREPM) {
        const int rg = blk / 12, jt = blk % 12;
        const int b0 = rg * 4;
        const int proj = jt >> 2, rowbase = (jt & 3) * 64;
        if (proj == 0)
            prep_tile<768>(query, W_ent, b_ent, b0, rowbase, 0, qe, qe8, smem);
        else if (proj == 1)
            prep_tile<256>(query, W_left, b_left, b0, rowbase, 256, ql, ql8, smem);
        else
            prep_tile<256>(query, W_right, b_right, b0, rowbase, 256, qr, qr8, smem);
        return;
    }
    if (blk >= NPREPM + nconv) {
        const int idx = (blk - NPREPM - nconv) * 256 + t;
        if (idx < 32768) {
            const int q = idx >> 6, e4 = idx & 63;
            float4 v = *(const float4*)(lc + (size_t)q * 768 + e4 * 4);
            *(float4*)(out + (size_t)q * 768 + e4 * 4) = v;
        } else {
            const int j = idx - 32768;
            const int q = j >> 6, e4 = j & 63;
            float4 v = *(const float4*)(rc + (size_t)q * 768 + 512 + e4 * 4);
            *(float4*)(out + (size_t)393216 + q * 768 + 512 + e4 * 4) = v;
        }
        return;
    }

    // ---- conv: fp32 tables -> per-64-row-group fp8 MX blobs (16 KB each)
    //   K blob: [sub 2][kc 4][kb 2][n 32][32 B]
    //   V blob: [et 8][kb 2][n 32][j 32]  (rows permuted to MFMA C-layout)
    const int cidx = blk - NPREPM;
    const int x = cidx >> 2, y = cidx & 3;
    const float* in; u8* outT; u8* outB; int R; int g;
    if (x < 1563) {
        in = entF; outT = entT; outB = entB; R = ENT_N; g = x;
    } else {
        in = relF; outT = relT; outB = relB; R = REL_N; g = x - 1563;
    }
    const int r0 = g * 64;
    float* tile = smem;            // [64][65]
    const int e0 = y * 64;

    const int eg = t & 7, rowb = t >> 3;
#pragma unroll
    for (int item = 0; item < 2; ++item) {
        const int r = rowb + item * 32;
        float4 a, b;
        if ((r0 + r) < R) {
            const float* src = in + (size_t)(r0 + r) * 256 + e0 + eg * 8;
            a = *(const float4*)src;
            b = *(const float4*)(src + 4);
        } else { a = make_float4(0.f, 0.f, 0.f, 0.f); b = a; }
        float* dst = tile + r * 65 + eg * 8;
        dst[0] = a.x; dst[1] = a.y; dst[2] = a.z; dst[3] = a.w;
        dst[4] = b.x; dst[5] = b.y; dst[6] = b.z; dst[7] = b.w;
    }
    __syncthreads();

    // ---- K emit: kc = y, all 64 rows ----
    {
        const int n2 = t >> 2, piece = t & 3;
        const int sub = n2 >> 5, nn = n2 & 31;
        const int kbk = piece >> 1, jh = piece & 1;
        const float* src = tile + n2 * 65 + kbk * 32 + jh * 16;
        u32 xx; uint4 o;
        xx = __builtin_amdgcn_cvt_pk_fp8_f32(src[0], src[1], 0, false);
        o.x = __builtin_amdgcn_cvt_pk_fp8_f32(src[2], src[3], xx, true);
        xx = __builtin_amdgcn_cvt_pk_fp8_f32(src[4], src[5], 0, false);
        o.y = __builtin_amdgcn_cvt_pk_fp8_f32(src[6], src[7], xx, true);
        xx = __builtin_amdgcn_cvt_pk_fp8_f32(src[8], src[9], 0, false);
        o.z = __builtin_amdgcn_cvt_pk_fp8_f32(src[10], src[11], xx, true);
        xx = __builtin_amdgcn_cvt_pk_fp8_f32(src[12], src[13], 0, false);
        o.w = __builtin_amdgcn_cvt_pk_fp8_f32(src[14], src[15], xx, true);
        *(uint4*)(outB + (size_t)g * 16384 + sub * 8192 +
                  (size_t)y * 2048 + kbk * 1024 + nn * 32 + jh * 16) = o;
    }
    // ---- V emit: et = 2y, 2y+1, all 64 k-slots ----
    {
        const int etl = t >> 7, kbv = (t >> 6) & 1;
        const int nv = (t >> 1) & 31, jh = t & 1;
        const int colL = etl * 32 + nv;
        float v[16];
#pragma unroll
        for (int i = 0; i < 16; ++i) {
            const int row = jh * 32 + (i & 3) + 8 * (i >> 2) + 4 * kbv;
            v[i] = tile[row * 65 + colL];
        }
        u32 xx; uint4 o;
        xx = __builtin_amdgcn_cvt_pk_fp8_f32(v[0], v[1], 0, false);
        o.x = __builtin_amdgcn_cvt_pk_fp8_f32(v[2], v[3], xx, true);
        xx = __builtin_amdgcn_cvt_pk_fp8_f32(v[4], v[5], 0, false);
        o.y = __builtin_amdgcn_cvt_pk_fp8_f32(v[6], v[7], xx, true);
        xx = __builtin_amdgcn_cvt_pk_fp8_f32(v[8], v[9], 0, false);
        o.z = __builtin_amdgcn_cvt_pk_fp8_f32(v[10], v[11], xx, true);
        xx = __builtin_amdgcn_cvt_pk_fp8_f32(v[12], v[13], 0, false);
        o.w = __builtin_amdgcn_cvt_pk_fp8_f32(v[14], v[15], xx, true);
        *(uint4*)(outT + (size_t)g * 16384 +
                  (size_t)(y * 2 + etl) * 2048 +
                  kbv * 1024 + nv * 32 + jh * 16) = o;
    }
}

// ---------------------------------------------------------------------------
// flash_combine: flash10 body (verbatim) + R7-proven grid barrier + combine
// phase (R7 phase-3 verbatim, grid-strided). Removes one dispatch boundary
// (~15-20 us measured) and the combine launch. Both phases are natural
// 512-block / 64KB-LDS shapes (unlike conv/prep — R7's mistake).
// ---------------------------------------------------------------------------
__global__ __launch_bounds__(256, 2) void flash_combine(
    const u8* __restrict__ qeP, const u8* __restrict__ qlP,
    const u8* __restrict__ qrP,
    const u8* __restrict__ entB, const u8* __restrict__ relB,
    const u8* __restrict__ entT, const u8* __restrict__ relT,
    float* __restrict__ entL, float* __restrict__ relLL,
    float* __restrict__ relLR,
    u16* __restrict__ entO, u16* __restrict__ relOL, u16* __restrict__ relOR,
    float* __restrict__ out, u32* __restrict__ cnt0)
{
    const int tid = threadIdx.x;
    const int w = tid >> 6;
    const int lane = tid & 63;
    const int n = lane & 31;
    const int kb = lane >> 5;

    __shared__ __align__(16) u8 lds[65536];
    u16* lds16 = (u16*)lds;

    // ================= phase A: flash =================
    {
        int qt, c, stride, nt, Nrows;
        const u8* qbf; const u8* tabB; const u8* tabT;
        float* pL; u16* pO;
        {
            const int id = blockIdx.x;
            if (id < 480) {
                qt = id / 120; c = id % 120;
                stride = 120; nt = (c < 3) ? 14 : 13;   // 1563 rowgroups
                Nrows = ENT_N;
                qbf = qeP; tabB = entB; tabT = entT; pL = entL; pO = entO;
            } else {
                const int r = id - 480;
                qt = (r >> 2) & 3; c = r & 3;
                stride = 4; nt = 8;                      // 32 rowgroups
                Nrows = REL_N;
                tabB = relB; tabT = relT;
                if (r < 16) { qbf = qlP; pL = relLL; pO = relOL; }
                else        { qbf = qrP; pL = relLR; pO = relOR; }
            }
        }
        const int q0 = qt * 128;
        const int qw = q0 + w * 32;

        const u8* qrow = qbf + (size_t)(qw + n) * 256;
        i32x8 qf[4];
#pragma unroll
        for (int kc = 0; kc < 4; ++kc) {
            uint4 a = *(const uint4*)(qrow + kc * 64 + kb * 32);
            uint4 b = *(const uint4*)(qrow + kc * 64 + kb * 32 + 16);
            qf[kc] = mk8(a, b);
        }

        f32x16 acc[8];
#pragma unroll
        for (int et = 0; et < 8; ++et)
#pragma unroll
            for (int i = 0; i < 16; ++i) acc[et][i] = 0.f;
        float l_run = 0.f;

        auto stage = [&](int buf, int g) {
            u8* sK = lds + buf * 32768;
            u8* sV = sK + 16384;
            const u8* ksrc = tabB + (size_t)g * 16384 + w * 4096 + (size_t)lane * 16;
            const u8* vsrc = tabT + (size_t)g * 16384 + w * 4096 + (size_t)lane * 16;
#pragma unroll
            for (int o = 0; o < 4096; o += 1024) {
                __builtin_amdgcn_global_load_lds((gvoid*)(ksrc + o),
                                                 (svoid*)(sK + w * 4096 + o), 16, 0, 0);
                __builtin_amdgcn_global_load_lds((gvoid*)(vsrc + o),
                                                 (svoid*)(sV + w * 4096 + o), 16, 0, 0);
            }
        };

        int rt = c;
        stage(0, rt);
        __syncthreads();

        for (int k = 0; k < nt; ++k) {
            if (k + 1 < nt) stage((k + 1) & 1, rt + stride);

            const u8* sK = lds + (k & 1) * 32768;
            const u8* sV = sK + 16384;
            const int gr = rt * 64;

            f32x16 L0, L1;
#pragma unroll
            for (int i = 0; i < 16; ++i) { L0[i] = 0.f; L1[i] = 0.f; }
            const u8* kbase = sK + kb * 1024 + n * 32;
#pragma unroll
            for (int kc = 0; kc < 4; ++kc) {
                uint4 a0 = *(const uint4*)(kbase + kc * 2048);
                uint4 a1 = *(const uint4*)(kbase + kc * 2048 + 16);
                L0 = __builtin_amdgcn_mfma_scale_f32_32x32x64_f8f6f4(
                    mk8(a0, a1), qf[kc], L0, 0, 0, 0, 0x7f7f7f7f, 0, 0x7f7f7f7f);
                uint4 b0 = *(const uint4*)(kbase + 8192 + kc * 2048);
                uint4 b1 = *(const uint4*)(kbase + 8192 + kc * 2048 + 16);
                L1 = __builtin_amdgcn_mfma_scale_f32_32x32x64_f8f6f4(
                    mk8(b0, b1), qf[kc], L1, 0, 0, 0, 0x7f7f7f7f, 0, 0x7f7f7f7f);
            }
            if (gr + 64 > Nrows) {
#pragma unroll
                for (int r = 0; r < 16; ++r) {
                    const int row = (r & 3) + 8 * (r >> 2) + 4 * kb;
                    if (gr + row >= Nrows)      L0[r] = -1e30f;
                    if (gr + 32 + row >= Nrows) L1[r] = -1e30f;
                }
            }
            float rs = 0.f;
#pragma unroll
            for (int r = 0; r < 16; ++r) {
                const float p0 = __expf(L0[r]); L0[r] = p0; rs += p0;
                const float p1 = __expf(L1[r]); L1[r] = p1; rs += p1;
            }
            rs += __shfl_xor(rs, 32);
            l_run += rs;
            u32 p[8];
#pragma unroll
            for (int i = 0; i < 4; ++i) {
                u32 x = __builtin_amdgcn_cvt_pk_fp8_f32(L0[i * 4 + 0], L0[i * 4 + 1], 0, false);
                p[i] = __builtin_amdgcn_cvt_pk_fp8_f32(L0[i * 4 + 2], L0[i * 4 + 3], x, true);
                u32 y = __builtin_amdgcn_cvt_pk_fp8_f32(L1[i * 4 + 0], L1[i * 4 + 1], 0, false);
                p[i + 4] = __builtin_amdgcn_cvt_pk_fp8_f32(L1[i * 4 + 2], L1[i * 4 + 3], y, true);
            }
            uint4 pa; pa.x = p[0]; pa.y = p[1]; pa.z = p[2]; pa.w = p[3];
            uint4 pb; pb.x = p[4]; pb.y = p[5]; pb.z = p[6]; pb.w = p[7];
            const i32x8 bv = mk8(pa, pb);
            const u8* vbase = sV + kb * 1024 + n * 32;
#pragma unroll
            for (int et = 0; et < 8; ++et) {
                uint4 v0 = *(const uint4*)(vbase + et * 2048);
                uint4 v1 = *(const uint4*)(vbase + et * 2048 + 16);
                acc[et] = __builtin_amdgcn_mfma_scale_f32_32x32x64_f8f6f4(
                    mk8(v0, v1), bv, acc[et], 0, 0, 0, 0x7f7f7f7f, 0, 0x7f7f7f7f);
            }
            rt += stride;
            __syncthreads();
        }

        if (lane < 32) pL[(size_t)c * 512 + qw + n] = l_run;

        for (int half = 0; half < 2; ++half) {
            __syncthreads();
            if ((w >> 1) == half) {
                u16* rgn = lds16 + (w & 1) * 8448;   // [32 q][264]
#pragma unroll
                for (int et = 0; et < 8; ++et)
#pragma unroll
                    for (int a2 = 0; a2 < 4; ++a2) {
                        bf16 h0 = (bf16)acc[et][a2 * 4 + 0];
                        bf16 h1 = (bf16)acc[et][a2 * 4 + 1];
                        bf16 h2 = (bf16)acc[et][a2 * 4 + 2];
                        bf16 h3 = (bf16)acc[et][a2 * 4 + 3];
                        uint2 pk;
                        pk.x = ((u32)(*(u16*)&h1) << 16) | (u32)(*(u16*)&h0);
                        pk.y = ((u32)(*(u16*)&h3) << 16) | (u32)(*(u16*)&h2);
                        *(uint2*)(rgn + n * 264 + et * 32 + 8 * a2 + 4 * kb) = pk;
                    }
            }
            __syncthreads();
#pragma unroll
            for (int rg = 0; rg < 2; ++rg) {
                const int qt2 = q0 + (half * 2 + rg) * 32;
                const u16* src = lds16 + rg * 8448;
                const int qq = tid >> 3, e0 = (tid & 7) * 32;
#pragma unroll
                for (int i = 0; i < 4; ++i) {
                    const u16* sp = src + qq * 264 + e0 + i * 8;
                    uint2 a = *(const uint2*)(sp);
                    uint2 b = *(const uint2*)(sp + 4);
                    uint4 wv; wv.x = a.x; wv.y = a.y; wv.z = b.x; wv.w = b.y;
                    *(uint4*)(pO + ((size_t)c * 512 + qt2 + qq) * 256 + e0 + i * 8) = wv;
                }
            }
        }
    }
    grid_barrier(cnt0);

    // ================= phase B: combine (768 virtual blocks) =================
    {
        const int t = threadIdx.x;
        typedef float RedT[32][4][11];
        RedT* red = (RedT*)lds;       // [2][32][4][11] = 11264 B
        for (int v = blockIdx.x; v < 768; v += NBLK) {
            __syncthreads();
            const int gx = v & 255, gy = v >> 8;
            const u16* pO; const float* pl; int CH, baseA, baseB;
            if (gy == 0) { pO = entO; pl = entL; CH = ENT_CH; baseA = 512; baseB = 393216; }
            else if (gy == 1) { pO = relOL; pl = relLL; CH = REL_CH; baseA = 256; baseB = -1; }
            else { pO = relOR; pl = relLR; CH = REL_CH; baseA = 393472; baseB = -1; }

            const int qi = t >> 7;
            const int e0g = (t >> 2) & 31;
            const int seg = t & 3;
            const int q = gx * 2 + qi;
            const int e0 = e0g * 8;
            const int cnt = CH >> 2;
            const int cbeg = seg * cnt;

            float s = 0.f;
            float a[8];
#pragma unroll
            for (int k = 0; k < 8; ++k) a[k] = 0.f;
#pragma unroll 6
            for (int c = cbeg; c < cbeg + cnt; ++c) {
                s += pl[(size_t)c * 512 + q];
                const uint4 wv = *(const uint4*)(pO + ((size_t)c * 512 + q) * 256 + e0);
                const u32 ww[4] = {wv.x, wv.y, wv.z, wv.w};
#pragma unroll
                for (int p = 0; p < 4; ++p) {
                    a[p * 2]     += __uint_as_float((ww[p] & 0xffffu) << 16);
                    a[p * 2 + 1] += __uint_as_float(ww[p] & 0xffff0000u);
                }
            }

            float* slot = red[qi][e0g][seg];
#pragma unroll
            for (int k = 0; k < 8; ++k) slot[k] = a[k];
            slot[8] = s;
            __syncthreads();
            if (seg == 0) {
                float st = 0.f;
                float b[8];
#pragma unroll
                for (int k = 0; k < 8; ++k) b[k] = 0.f;
#pragma unroll
                for (int sgi = 0; sgi < 4; ++sgi) {
                    const float* sl = red[qi][e0g][sgi];
                    st += sl[8];
#pragma unroll
                    for (int k = 0; k < 8; ++k) b[k] += sl[k];
                }
                const float inv = 1.f / st;
#pragma unroll
                for (int k = 0; k < 8; ++k) b[k] *= inv;
                float4 o1 = {b[0], b[1], b[2], b[3]};
                float4 o2 = {b[4], b[5], b[6], b[7]};
                *(float4*)(out + (size_t)baseA + (size_t)q * 768 + e0) = o1;
                *(float4*)(out + (size_t)baseA + (size_t)q * 768 + e0 + 4) = o2;
                if (baseB >= 0) {
                    *(float4*)(out + (size_t)baseB + (size_t)q * 768 + e0) = o1;
                    *(float4*)(out + (size_t)baseB + (size_t)q * 768 + e0 + 4) = o2;
                }
            }
        }
    }
}

// ---------------------------------------------------------------------------
// Fallback (small ws): fp32 online-softmax attend, bf16 q input.
// ---------------------------------------------------------------------------
__global__ __launch_bounds__(256) void attend_simple(
    const bf16* __restrict__ qbf, const float* __restrict__ tab, int Nrows,
    float* __restrict__ out, int baseA, int baseB)
{
    const int q = blockIdx.x;
    const int t = threadIdx.x, wave = t >> 6, lane = t & 63;
    float qv[4];
#pragma unroll
    for (int i = 0; i < 4; ++i) qv[i] = (float)qbf[(size_t)q * 256 + lane + 64 * i];
    float m = -INFINITY, l = 0.f, o[4] = {0.f, 0.f, 0.f, 0.f};
    for (int r = wave; r < Nrows; r += 4) {
        const float* row = tab + (size_t)r * 256;
        float d = 0.f;
#pragma unroll
        for (int i = 0; i < 4; ++i) d += qv[i] * row[lane + 64 * i];
#pragma unroll
        for (int s = 32; s; s >>= 1) d += __shfl_xor(d, s);
        const float mn = fmaxf(m, d);
        const float al = __expf(m - mn);
        const float p = __expf(d - mn);
#pragma unroll
        for (int i = 0; i < 4; ++i) o[i] = o[i] * al + p * row[lane + 64 * i];
        l = l * al + p; m = mn;
    }
    __shared__ float sm[4], sl[4], so[4][256];
    if (lane == 0) { sm[wave] = m; sl[wave] = l; }
#pragma unroll
    for (int i = 0; i < 4; ++i) so[wave][lane + 64 * i] = o[i];
    __syncthreads();
    const float M = fmaxf(fmaxf(sm[0], sm[1]), fmaxf(sm[2], sm[3]));
    const float w0 = __expf(sm[0] - M), w1 = __expf(sm[1] - M);
    const float w2 = __expf(sm[2] - M), w3 = __expf(sm[3] - M);
    const float L = w0 * sl[0] + w1 * sl[1] + w2 * sl[2] + w3 * sl[3];
    const float a = (w0 * so[0][t] + w1 * so[1][t] + w2 * so[2][t] + w3 * so[3][t]) / L;
    out[(size_t)baseA + (size_t)q * 768 + t] = a;
    if (baseB >= 0) out[(size_t)baseB + (size_t)q * 768 + t] = a;
}

// ---------------------------------------------------------------------------
extern "C" void kernel_launch(void* const* d_in, const int* in_sizes, int n_in,
                              void* d_out, int out_size, void* d_ws, size_t ws_size,
                              hipStream_t stream)
{
    const float* left_child  = (const float*)d_in[0];
    const float* right_child = (const float*)d_in[1];
    const float* query       = (const float*)d_in[2];
    const float* ent_emb     = (const float*)d_in[3];
    const float* rel_emb     = (const float*)d_in[4];
    const float* W_left      = (const float*)d_in[5];
    const float* b_left      = (const float*)d_in[6];
    const float* W_right     = (const float*)d_in[7];
    const float* b_right     = (const float*)d_in[8];
    const float* W_ent       = (const float*)d_in[9];
    const float* b_ent       = (const float*)d_in[10];
    float* out = (float*)d_out;
    char* ws = (char*)d_ws;

    // ws layout (bytes)
    bf16* qe_bf = (bf16*)(ws + 0);            //    262,144 (fallback)
    bf16* ql_bf = (bf16*)(ws + 262144);       //    262,144
    bf16* qr_bf = (bf16*)(ws + 524288);       //    262,144
    u8*   qe8   = (u8*)(ws + 786432);         //    131,072
    u8*   ql8   = (u8*)(ws + 917504);         //    131,072
    u8*   qr8   = (u8*)(ws + 1048576);        //    131,072
    u8*   entT8 = (u8*)(ws + 1179648);        // 25,608,192 (1563 grp x 16 KB)
    u8*   relT8 = (u8*)(ws + 26787840);       //    524,288 (32 grp x 16 KB)
    u8*   entB8 = (u8*)(ws + 27312128);       // 25,608,192
    u8*   relB8 = (u8*)(ws + 52920320);       //    524,288
    float* entL = (float*)(ws + 53444608);    //    245,760 (120*512*4)
    u16*  entO  = (u16*)(ws + 53690368);      // 31,457,280 (120*512*256*2)
    float* relLL = (float*)(ws + 85147648);   //      8,192
    float* relLR = (float*)(ws + 85155840);   //      8,192
    u16*  relOL = (u16*)(ws + 85164032);      //  1,048,576
    u16*  relOR = (u16*)(ws + 86212608);      //  1,048,576
    u32*  cnts  = (u32*)(ws + 87261184);      //        256 (barrier counter)
    const size_t WS_FULL = 87261440;
    const size_t WS_FALLBACK = 786432;

    if (ws_size >= WS_FULL) {
        hipMemsetAsync((void*)cnts, 0, 256, stream);   // zero barrier counter
        prep_conv<<<dim3(NPREPM + NITEMS + NCOPY), dim3(256), 0, stream>>>(
            query, W_left, b_left, W_right, b_right, W_ent, b_ent,
            left_child, right_child, qe_bf, ql_bf, qr_bf, qe8, ql8, qr8, out,
            ent_emb, rel_emb, entT8, entB8, relT8, relB8, NITEMS);
        flash_combine<<<dim3(NBLK), dim3(256), 0, stream>>>(
            qe8, ql8, qr8, entB8, relB8, entT8, relT8,
            entL, relLL, relLR, entO, relOL, relOR, out, cnts);
    } else if (ws_size >= WS_FALLBACK) {
        prep_conv<<<dim3(NPREPM + NCOPY), dim3(256), 0, stream>>>(
            query, W_left, b_left, W_right, b_right, W_ent, b_ent,
            left_child, right_child, qe_bf, ql_bf, qr_bf, qe8, ql8, qr8, out,
            ent_emb, rel_emb, (u8*)ws, (u8*)ws, (u8*)ws, (u8*)ws, 0);
        attend_simple<<<dim3(512), dim3(256), 0, stream>>>(qe_bf, ent_emb, ENT_N, out, 512, 393216);
        attend_simple<<<dim3(512), dim3(256), 0, stream>>>(ql_bf, rel_emb, REL_N, out, 256, -1);
        attend_simple<<<dim3(512), dim3(256), 0, stream>>>(qr_bf, rel_emb, REL_N, out, 393472, -1);
    }
    (void)in_sizes; (void)n_in; (void)out_size;
}

// Round 11
// 254.051 us; speedup vs baseline: 1.2532x; 1.2532x over previous
//
#include <hip/hip_runtime.h>
#include <hip/hip_bf16.h>
#include <math.h>

typedef __bf16 bf16;
typedef unsigned short u16;
typedef unsigned int u32;
typedef unsigned long long u64;
typedef long long i64;
typedef unsigned char u8;
typedef __attribute__((ext_vector_type(16))) float f32x16;
typedef __attribute__((ext_vector_type(8))) int i32x8;
typedef __attribute__((address_space(1))) void gvoid;
typedef __attribute__((address_space(3))) void svoid;

#define ENT_N 100000
#define REL_N 2000
#define ENT_CH 120        // partial chunks per qt (ent)
#define REL_CH 4          // partial chunks per (side,qt) (rel)

#define NPREPM 1536       // prep matmul blocks (128 rowgroups x 12 j-tiles)
#define NITEMS 6380       // conv items (1595 rowgroups x 4 e-chunks)
#define NCOPY  256        // passthrough copy blocks

static __device__ __forceinline__ i32x8 mk8(uint4 a, uint4 b) {
    i32x8 r;
    r[0] = (int)a.x; r[1] = (int)a.y; r[2] = (int)a.z; r[3] = (int)a.w;
    r[4] = (int)b.x; r[5] = (int)b.y; r[6] = (int)b.z; r[7] = (int)b.w;
    return r;
}

// ---------------------------------------------------------------------------
// prep projection tile (pipelined, verified R4): 64 out cols x 4 q-rows,
// W staged via 2-buffer LDS ping-pong, one barrier per 32-k chunk.
// ---------------------------------------------------------------------------
template<int KLEN>
static __device__ __forceinline__ void prep_tile(
    const float* __restrict__ query, const float* __restrict__ W,
    const float* __restrict__ bias, int b0, int rowbase, int qwoff,
    bf16* __restrict__ outBf, u8* __restrict__ out8, float* smem)
{
    const int t = threadIdx.x;
    float* qs = smem;               // [4][KLEN]
    float* Wl = smem + 4 * KLEN;    // 2 x [64][33]

#pragma unroll
    for (int i = 0; i < 4 * KLEN / 256; ++i) {
        const int l = t + 256 * i;
        const int r = l / KLEN, k = l % KLEN;
        qs[l] = query[(size_t)(b0 + r) * 768 + qwoff + k];
    }

    const int j = t & 63, r = t >> 6;
    const int srow = t >> 3, skq = t & 7;
    const float* wbase = W + (size_t)rowbase * KLEN;

    float4 v0, v1;
    auto wload = [&](int c) {
        v0 = *(const float4*)(wbase + (size_t)srow * KLEN + c * 32 + skq * 4);
        v1 = *(const float4*)(wbase + (size_t)(srow + 32) * KLEN + c * 32 + skq * 4);
    };
    auto wstore = [&](float* dst) {
        float* d0 = dst + srow * 33 + skq * 4;
        d0[0] = v0.x; d0[1] = v0.y; d0[2] = v0.z; d0[3] = v0.w;
        float* d1 = dst + (srow + 32) * 33 + skq * 4;
        d1[0] = v1.x; d1[1] = v1.y; d1[2] = v1.z; d1[3] = v1.w;
    };

    float acc = 0.f;
    wload(0);
    wstore(Wl);
    constexpr int NC = KLEN / 32;
    for (int c = 0; c < NC; ++c) {
        if (c + 1 < NC) wload(c + 1);
        __syncthreads();
        const float* wr = Wl + (c & 1) * 2112 + j * 33;
        const float* qr = qs + r * KLEN + c * 32;
#pragma unroll
        for (int k = 0; k < 32; ++k) acc += wr[k] * qr[k];
        if (c + 1 < NC) wstore(Wl + ((c + 1) & 1) * 2112);
    }
    acc += bias[rowbase + j];

    const size_t o = (size_t)(b0 + r) * 256 + rowbase + j;
    outBf[o] = (bf16)acc;
    out8[o] = (u8)__builtin_amdgcn_cvt_pk_fp8_f32(acc, acc, 0, false);
}

// ---------------------------------------------------------------------------
// prep_conv (R4 verbatim — best measured variant, 65.5 us):
//   blocks [0, NPREPM)             : projection tiles (pipelined)
//   blocks [NPREPM, NPREPM+nconv)  : conv items one-per-block
//   blocks [NPREPM+nconv, +NCOPY)  : passthrough copies
// ---------------------------------------------------------------------------
__global__ __launch_bounds__(256) void prep_conv(
    const float* __restrict__ query,
    const float* __restrict__ W_left, const float* __restrict__ b_left,
    const float* __restrict__ W_right, const float* __restrict__ b_right,
    const float* __restrict__ W_ent, const float* __restrict__ b_ent,
    const float* __restrict__ lc, const float* __restrict__ rc,
    bf16* __restrict__ qe, bf16* __restrict__ ql, bf16* __restrict__ qr,
    u8* __restrict__ qe8, u8* __restrict__ ql8, u8* __restrict__ qr8,
    float* __restrict__ out,
    const float* __restrict__ entF, const float* __restrict__ relF,
    u8* __restrict__ entT, u8* __restrict__ entB,
    u8* __restrict__ relT, u8* __restrict__ relB,
    int nconv)
{
    __shared__ float smem[7296];    // prep: 3072+4224; conv tile: 4160
    const int blk = blockIdx.x;
    const int t = threadIdx.x;

    if (blk < NPREPM) {
        const int rg = blk / 12, jt = blk % 12;
        const int b0 = rg * 4;
        const int proj = jt >> 2, rowbase = (jt & 3) * 64;
        if (proj == 0)
            prep_tile<768>(query, W_ent, b_ent, b0, rowbase, 0, qe, qe8, smem);
        else if (proj == 1)
            prep_tile<256>(query, W_left, b_left, b0, rowbase, 256, ql, ql8, smem);
        else
            prep_tile<256>(query, W_right, b_right, b0, rowbase, 256, qr, qr8, smem);
        return;
    }
    if (blk >= NPREPM + nconv) {
        const int idx = (blk - NPREPM - nconv) * 256 + t;
        if (idx < 32768) {
            const int q = idx >> 6, e4 = idx & 63;
            float4 v = *(const float4*)(lc + (size_t)q * 768 + e4 * 4);
            *(float4*)(out + (size_t)q * 768 + e4 * 4) = v;
        } else {
            const int j = idx - 32768;
            const int q = j >> 6, e4 = j & 63;
            float4 v = *(const float4*)(rc + (size_t)q * 768 + 512 + e4 * 4);
            *(float4*)(out + (size_t)393216 + q * 768 + 512 + e4 * 4) = v;
        }
        return;
    }

    // ---- conv: fp32 tables -> per-64-row-group fp8 MX blobs (16 KB each)
    //   K blob: [sub 2][kc 4][kb 2][n 32][32 B]
    //   V blob: [et 8][kb 2][n 32][j 32]  (rows permuted to MFMA C-layout)
    const int cidx = blk - NPREPM;
    const int x = cidx >> 2, y = cidx & 3;
    const float* in; u8* outT; u8* outB; int R; int g;
    if (x < 1563) {
        in = entF; outT = entT; outB = entB; R = ENT_N; g = x;
    } else {
        in = relF; outT = relT; outB = relB; R = REL_N; g = x - 1563;
    }
    const int r0 = g * 64;
    float* tile = smem;            // [64][65]
    const int e0 = y * 64;

    const int eg = t & 7, rowb = t >> 3;
#pragma unroll
    for (int item = 0; item < 2; ++item) {
        const int r = rowb + item * 32;
        float4 a, b;
        if ((r0 + r) < R) {
            const float* src = in + (size_t)(r0 + r) * 256 + e0 + eg * 8;
            a = *(const float4*)src;
            b = *(const float4*)(src + 4);
        } else { a = make_float4(0.f, 0.f, 0.f, 0.f); b = a; }
        float* dst = tile + r * 65 + eg * 8;
        dst[0] = a.x; dst[1] = a.y; dst[2] = a.z; dst[3] = a.w;
        dst[4] = b.x; dst[5] = b.y; dst[6] = b.z; dst[7] = b.w;
    }
    __syncthreads();

    // ---- K emit: kc = y, all 64 rows ----
    {
        const int n2 = t >> 2, piece = t & 3;
        const int sub = n2 >> 5, nn = n2 & 31;
        const int kbk = piece >> 1, jh = piece & 1;
        const float* src = tile + n2 * 65 + kbk * 32 + jh * 16;
        u32 xx; uint4 o;
        xx = __builtin_amdgcn_cvt_pk_fp8_f32(src[0], src[1], 0, false);
        o.x = __builtin_amdgcn_cvt_pk_fp8_f32(src[2], src[3], xx, true);
        xx = __builtin_amdgcn_cvt_pk_fp8_f32(src[4], src[5], 0, false);
        o.y = __builtin_amdgcn_cvt_pk_fp8_f32(src[6], src[7], xx, true);
        xx = __builtin_amdgcn_cvt_pk_fp8_f32(src[8], src[9], 0, false);
        o.z = __builtin_amdgcn_cvt_pk_fp8_f32(src[10], src[11], xx, true);
        xx = __builtin_amdgcn_cvt_pk_fp8_f32(src[12], src[13], 0, false);
        o.w = __builtin_amdgcn_cvt_pk_fp8_f32(src[14], src[15], xx, true);
        *(uint4*)(outB + (size_t)g * 16384 + sub * 8192 +
                  (size_t)y * 2048 + kbk * 1024 + nn * 32 + jh * 16) = o;
    }
    // ---- V emit: et = 2y, 2y+1, all 64 k-slots ----
    {
        const int etl = t >> 7, kbv = (t >> 6) & 1;
        const int nv = (t >> 1) & 31, jh = t & 1;
        const int colL = etl * 32 + nv;
        float v[16];
#pragma unroll
        for (int i = 0; i < 16; ++i) {
            const int row = jh * 32 + (i & 3) + 8 * (i >> 2) + 4 * kbv;
            v[i] = tile[row * 65 + colL];
        }
        u32 xx; uint4 o;
        xx = __builtin_amdgcn_cvt_pk_fp8_f32(v[0], v[1], 0, false);
        o.x = __builtin_amdgcn_cvt_pk_fp8_f32(v[2], v[3], xx, true);
        xx = __builtin_amdgcn_cvt_pk_fp8_f32(v[4], v[5], 0, false);
        o.y = __builtin_amdgcn_cvt_pk_fp8_f32(v[6], v[7], xx, true);
        xx = __builtin_amdgcn_cvt_pk_fp8_f32(v[8], v[9], 0, false);
        o.z = __builtin_amdgcn_cvt_pk_fp8_f32(v[10], v[11], xx, true);
        xx = __builtin_amdgcn_cvt_pk_fp8_f32(v[12], v[13], 0, false);
        o.w = __builtin_amdgcn_cvt_pk_fp8_f32(v[14], v[15], xx, true);
        *(uint4*)(outT + (size_t)g * 16384 +
                  (size_t)(y * 2 + etl) * 2048 +
                  kbv * 1024 + nv * 32 + jh * 16) = o;
    }
}

// ---------------------------------------------------------------------------
// flash11: barrier-free, LDS-staging-free flash. R9's counters showed the
// staged version is ~80% stall (MfmaUtil 7.7%, VALUBusy 8.8%): every K-tile
// pays a vmcnt(0)+barrier drain across 4 lockstep waves at 2 blocks/CU.
// The blobs are L2/L3-resident and conv's layouts make each wave's fragment
// read a contiguous 2 KB global segment — identical offsets to the old LDS
// reads, so A-fragments load straight from global (guide Common-mistake #7:
// don't stage what cache-fits). No main-loop barriers: 8 waves/CU run free;
// L1 catches the 4-waves-same-bytes redundancy. LDS = 33 KB epilogue only.
// ---------------------------------------------------------------------------
__global__ __launch_bounds__(256) void flash11(
    const u8* __restrict__ qeP, const u8* __restrict__ qlP,
    const u8* __restrict__ qrP,
    const u8* __restrict__ entB, const u8* __restrict__ relB,
    const u8* __restrict__ entT, const u8* __restrict__ relT,
    float* __restrict__ entL, float* __restrict__ relLL,
    float* __restrict__ relLR,
    u16* __restrict__ entO, u16* __restrict__ relOL, u16* __restrict__ relOR)
{
    const int tid = threadIdx.x;
    const int w = tid >> 6;
    const int lane = tid & 63;
    const int n = lane & 31;
    const int kb = lane >> 5;

    int qt, c, stride, nt, Nrows;
    const u8* qbf; const u8* tabB; const u8* tabT;
    float* pL; u16* pO;
    {
        const int id = blockIdx.x;
        if (id < 480) {
            qt = id / 120; c = id % 120;
            stride = 120; nt = (c < 3) ? 14 : 13;   // 1563 rowgroups
            Nrows = ENT_N;
            qbf = qeP; tabB = entB; tabT = entT; pL = entL; pO = entO;
        } else {
            const int r = id - 480;
            qt = (r >> 2) & 3; c = r & 3;
            stride = 4; nt = 8;                      // 32 rowgroups
            Nrows = REL_N;
            tabB = relB; tabT = relT;
            if (r < 16) { qbf = qlP; pL = relLL; pO = relOL; }
            else        { qbf = qrP; pL = relLR; pO = relOR; }
        }
    }
    const int q0 = qt * 128;
    const int qw = q0 + w * 32;

    __shared__ __align__(16) u16 lds16[16896];   // 33,792 B epilogue transpose

    const u8* qrow = qbf + (size_t)(qw + n) * 256;
    i32x8 qf[4];
#pragma unroll
    for (int kc = 0; kc < 4; ++kc) {
        uint4 a = *(const uint4*)(qrow + kc * 64 + kb * 32);
        uint4 b = *(const uint4*)(qrow + kc * 64 + kb * 32 + 16);
        qf[kc] = mk8(a, b);
    }

    f32x16 acc[8];
#pragma unroll
    for (int et = 0; et < 8; ++et)
#pragma unroll
        for (int i = 0; i < 16; ++i) acc[et][i] = 0.f;
    float l_run = 0.f;

    int rt = c;
    for (int k = 0; k < nt; ++k) {
        // wave-fragment base: lane (n,kb) -> contiguous 2 KB per (kc,sub)/et
        const u8* kbB = tabB + (size_t)rt * 16384 + kb * 1024 + n * 32;
        const u8* vbB = tabT + (size_t)rt * 16384 + kb * 1024 + n * 32;
        const int gr = rt * 64;

        // ---- logits^T for two 32-row subtiles (A-frags direct from L2) ----
        f32x16 L0, L1;
#pragma unroll
        for (int i = 0; i < 16; ++i) { L0[i] = 0.f; L1[i] = 0.f; }
#pragma unroll
        for (int kc = 0; kc < 4; ++kc) {
            uint4 a0 = *(const uint4*)(kbB + kc * 2048);
            uint4 a1 = *(const uint4*)(kbB + kc * 2048 + 16);
            L0 = __builtin_amdgcn_mfma_scale_f32_32x32x64_f8f6f4(
                mk8(a0, a1), qf[kc], L0, 0, 0, 0, 0x7f7f7f7f, 0, 0x7f7f7f7f);
            uint4 b0 = *(const uint4*)(kbB + 8192 + kc * 2048);
            uint4 b1 = *(const uint4*)(kbB + 8192 + kc * 2048 + 16);
            L1 = __builtin_amdgcn_mfma_scale_f32_32x32x64_f8f6f4(
                mk8(b0, b1), qf[kc], L1, 0, 0, 0, 0x7f7f7f7f, 0, 0x7f7f7f7f);
        }
        if (gr + 64 > Nrows) {
#pragma unroll
            for (int r = 0; r < 16; ++r) {
                const int row = (r & 3) + 8 * (r >> 2) + 4 * kb;
                if (gr + row >= Nrows)      L0[r] = -1e30f;
                if (gr + 32 + row >= Nrows) L1[r] = -1e30f;
            }
        }
        // ---- P = exp(L), row-sum ----
        float rs = 0.f;
#pragma unroll
        for (int r = 0; r < 16; ++r) {
            const float p0 = __expf(L0[r]); L0[r] = p0; rs += p0;
            const float p1 = __expf(L1[r]); L1[r] = p1; rs += p1;
        }
        rs += __shfl_xor(rs, 32);
        l_run += rs;
        // ---- P -> fp8 B-fragment (register order; V permutation matches) ----
        u32 p[8];
#pragma unroll
        for (int i = 0; i < 4; ++i) {
            u32 x = __builtin_amdgcn_cvt_pk_fp8_f32(L0[i * 4 + 0], L0[i * 4 + 1], 0, false);
            p[i] = __builtin_amdgcn_cvt_pk_fp8_f32(L0[i * 4 + 2], L0[i * 4 + 3], x, true);
            u32 y = __builtin_amdgcn_cvt_pk_fp8_f32(L1[i * 4 + 0], L1[i * 4 + 1], 0, false);
            p[i + 4] = __builtin_amdgcn_cvt_pk_fp8_f32(L1[i * 4 + 2], L1[i * 4 + 3], y, true);
        }
        uint4 pa; pa.x = p[0]; pa.y = p[1]; pa.z = p[2]; pa.w = p[3];
        uint4 pb; pb.x = p[4]; pb.y = p[5]; pb.z = p[6]; pb.w = p[7];
        const i32x8 bv = mk8(pa, pb);
        // ---- PV: O^T += V^T x P (V^T frags direct from L2) ----
#pragma unroll
        for (int et = 0; et < 8; ++et) {
            uint4 v0 = *(const uint4*)(vbB + et * 2048);
            uint4 v1 = *(const uint4*)(vbB + et * 2048 + 16);
            acc[et] = __builtin_amdgcn_mfma_scale_f32_32x32x64_f8f6f4(
                mk8(v0, v1), bv, acc[et], 0, 0, 0, 0x7f7f7f7f, 0, 0x7f7f7f7f);
        }
        rt += stride;
    }

    if (lane < 32) pL[(size_t)c * 512 + qw + n] = l_run;

    // ---- write partial O via LDS transpose (stride 264, two wave-pairs) ----
    for (int half = 0; half < 2; ++half) {
        __syncthreads();
        if ((w >> 1) == half) {
            u16* rgn = lds16 + (w & 1) * 8448;   // [32 q][264]
#pragma unroll
            for (int et = 0; et < 8; ++et)
#pragma unroll
                for (int a2 = 0; a2 < 4; ++a2) {
                    bf16 h0 = (bf16)acc[et][a2 * 4 + 0];
                    bf16 h1 = (bf16)acc[et][a2 * 4 + 1];
                    bf16 h2 = (bf16)acc[et][a2 * 4 + 2];
                    bf16 h3 = (bf16)acc[et][a2 * 4 + 3];
                    uint2 pk;
                    pk.x = ((u32)(*(u16*)&h1) << 16) | (u32)(*(u16*)&h0);
                    pk.y = ((u32)(*(u16*)&h3) << 16) | (u32)(*(u16*)&h2);
                    *(uint2*)(rgn + n * 264 + et * 32 + 8 * a2 + 4 * kb) = pk;
                }
        }
        __syncthreads();
#pragma unroll
        for (int rg = 0; rg < 2; ++rg) {
            const int qt2 = q0 + (half * 2 + rg) * 32;
            const u16* src = lds16 + rg * 8448;
            const int qq = tid >> 3, e0 = (tid & 7) * 32;
#pragma unroll
            for (int i = 0; i < 4; ++i) {
                const u16* sp = src + qq * 264 + e0 + i * 8;
                uint2 a = *(const uint2*)(sp);
                uint2 b = *(const uint2*)(sp + 4);
                uint4 wv; wv.x = a.x; wv.y = a.y; wv.z = b.x; wv.w = b.y;
                *(uint4*)(pO + ((size_t)c * 512 + qt2 + qq) * 256 + e0 + i * 8) = wv;
            }
        }
    }
}

// ---------------------------------------------------------------------------
// combine_all v2: grid (256, 3): y=0 ent (CH=120), y=1 relL, y=2 relR (CH=4).
// Block = 2 q; thread = (qi, e-group, c-segment of CH/4). l-sum fused,
// 4-way c-split shortens the load chain, LDS-reduce across segments.
// ---------------------------------------------------------------------------
__global__ __launch_bounds__(256) void combine_all(
    const u16* __restrict__ entO, const float* __restrict__ entL,
    const u16* __restrict__ relOL, const float* __restrict__ relLL,
    const u16* __restrict__ relOR, const float* __restrict__ relLR,
    float* __restrict__ out)
{
    const u16* pO; const float* pl; int CH, baseA, baseB;
    if (blockIdx.y == 0) { pO = entO; pl = entL; CH = ENT_CH; baseA = 512; baseB = 393216; }
    else if (blockIdx.y == 1) { pO = relOL; pl = relLL; CH = REL_CH; baseA = 256; baseB = -1; }
    else { pO = relOR; pl = relLR; CH = REL_CH; baseA = 393472; baseB = -1; }

    const int t = threadIdx.x;
    const int qi = t >> 7;            // 0..1
    const int e0g = (t >> 2) & 31;    // 0..31
    const int seg = t & 3;            // 0..3
    const int q = blockIdx.x * 2 + qi;
    const int e0 = e0g * 8;
    const int cnt = CH >> 2;
    const int cbeg = seg * cnt;

    float s = 0.f;
    float a[8];
#pragma unroll
    for (int k = 0; k < 8; ++k) a[k] = 0.f;
#pragma unroll 6
    for (int c = cbeg; c < cbeg + cnt; ++c) {
        s += pl[(size_t)c * 512 + q];
        const uint4 wv = *(const uint4*)(pO + ((size_t)c * 512 + q) * 256 + e0);
        const u32 ww[4] = {wv.x, wv.y, wv.z, wv.w};
#pragma unroll
        for (int p = 0; p < 4; ++p) {
            a[p * 2]     += __uint_as_float((ww[p] & 0xffffu) << 16);
            a[p * 2 + 1] += __uint_as_float(ww[p] & 0xffff0000u);
        }
    }

    __shared__ float red[2][32][4][11];   // pad 11: conflict-free writes
    float* slot = red[qi][e0g][seg];
#pragma unroll
    for (int k = 0; k < 8; ++k) slot[k] = a[k];
    slot[8] = s;
    __syncthreads();
    if (seg == 0) {
        float st = 0.f;
        float b[8];
#pragma unroll
        for (int k = 0; k < 8; ++k) b[k] = 0.f;
#pragma unroll
        for (int sgi = 0; sgi < 4; ++sgi) {
            const float* sl = red[qi][e0g][sgi];
            st += sl[8];
#pragma unroll
            for (int k = 0; k < 8; ++k) b[k] += sl[k];
        }
        const float inv = 1.f / st;
#pragma unroll
        for (int k = 0; k < 8; ++k) b[k] *= inv;
        float4 o1 = {b[0], b[1], b[2], b[3]};
        float4 o2 = {b[4], b[5], b[6], b[7]};
        *(float4*)(out + (size_t)baseA + (size_t)q * 768 + e0) = o1;
        *(float4*)(out + (size_t)baseA + (size_t)q * 768 + e0 + 4) = o2;
        if (baseB >= 0) {
            *(float4*)(out + (size_t)baseB + (size_t)q * 768 + e0) = o1;
            *(float4*)(out + (size_t)baseB + (size_t)q * 768 + e0 + 4) = o2;
        }
    }
}

// ---------------------------------------------------------------------------
// Fallback (small ws): fp32 online-softmax attend, bf16 q input.
// ---------------------------------------------------------------------------
__global__ __launch_bounds__(256) void attend_simple(
    const bf16* __restrict__ qbf, const float* __restrict__ tab, int Nrows,
    float* __restrict__ out, int baseA, int baseB)
{
    const int q = blockIdx.x;
    const int t = threadIdx.x, wave = t >> 6, lane = t & 63;
    float qv[4];
#pragma unroll
    for (int i = 0; i < 4; ++i) qv[i] = (float)qbf[(size_t)q * 256 + lane + 64 * i];
    float m = -INFINITY, l = 0.f, o[4] = {0.f, 0.f, 0.f, 0.f};
    for (int r = wave; r < Nrows; r += 4) {
        const float* row = tab + (size_t)r * 256;
        float d = 0.f;
#pragma unroll
        for (int i = 0; i < 4; ++i) d += qv[i] * row[lane + 64 * i];
#pragma unroll
        for (int s = 32; s; s >>= 1) d += __shfl_xor(d, s);
        const float mn = fmaxf(m, d);
        const float al = __expf(m - mn);
        const float p = __expf(d - mn);
#pragma unroll
        for (int i = 0; i < 4; ++i) o[i] = o[i] * al + p * row[lane + 64 * i];
        l = l * al + p; m = mn;
    }
    __shared__ float sm[4], sl[4], so[4][256];
    if (lane == 0) { sm[wave] = m; sl[wave] = l; }
#pragma unroll
    for (int i = 0; i < 4; ++i) so[wave][lane + 64 * i] = o[i];
    __syncthreads();
    const float M = fmaxf(fmaxf(sm[0], sm[1]), fmaxf(sm[2], sm[3]));
    const float w0 = __expf(sm[0] - M), w1 = __expf(sm[1] - M);
    const float w2 = __expf(sm[2] - M), w3 = __expf(sm[3] - M);
    const float L = w0 * sl[0] + w1 * sl[1] + w2 * sl[2] + w3 * sl[3];
    const float a = (w0 * so[0][t] + w1 * so[1][t] + w2 * so[2][t] + w3 * so[3][t]) / L;
    out[(size_t)baseA + (size_t)q * 768 + t] = a;
    if (baseB >= 0) out[(size_t)baseB + (size_t)q * 768 + t] = a;
}

// ---------------------------------------------------------------------------
extern "C" void kernel_launch(void* const* d_in, const int* in_sizes, int n_in,
                              void* d_out, int out_size, void* d_ws, size_t ws_size,
                              hipStream_t stream)
{
    const float* left_child  = (const float*)d_in[0];
    const float* right_child = (const float*)d_in[1];
    const float* query       = (const float*)d_in[2];
    const float* ent_emb     = (const float*)d_in[3];
    const float* rel_emb     = (const float*)d_in[4];
    const float* W_left      = (const float*)d_in[5];
    const float* b_left      = (const float*)d_in[6];
    const float* W_right     = (const float*)d_in[7];
    const float* b_right     = (const float*)d_in[8];
    const float* W_ent       = (const float*)d_in[9];
    const float* b_ent       = (const float*)d_in[10];
    float* out = (float*)d_out;
    char* ws = (char*)d_ws;

    // ws layout (bytes)
    bf16* qe_bf = (bf16*)(ws + 0);            //    262,144 (fallback)
    bf16* ql_bf = (bf16*)(ws + 262144);       //    262,144
    bf16* qr_bf = (bf16*)(ws + 524288);       //    262,144
    u8*   qe8   = (u8*)(ws + 786432);         //    131,072
    u8*   ql8   = (u8*)(ws + 917504);         //    131,072
    u8*   qr8   = (u8*)(ws + 1048576);        //    131,072
    u8*   entT8 = (u8*)(ws + 1179648);        // 25,608,192 (1563 grp x 16 KB)
    u8*   relT8 = (u8*)(ws + 26787840);       //    524,288 (32 grp x 16 KB)
    u8*   entB8 = (u8*)(ws + 27312128);       // 25,608,192
    u8*   relB8 = (u8*)(ws + 52920320);       //    524,288
    float* entL = (float*)(ws + 53444608);    //    245,760 (120*512*4)
    u16*  entO  = (u16*)(ws + 53690368);      // 31,457,280 (120*512*256*2)
    float* relLL = (float*)(ws + 85147648);   //      8,192
    float* relLR = (float*)(ws + 85155840);   //      8,192
    u16*  relOL = (u16*)(ws + 85164032);      //  1,048,576
    u16*  relOR = (u16*)(ws + 86212608);      //  1,048,576
    const size_t WS_FULL = 87261184;
    const size_t WS_FALLBACK = 786432;

    if (ws_size >= WS_FULL) {
        prep_conv<<<dim3(NPREPM + NITEMS + NCOPY), dim3(256), 0, stream>>>(
            query, W_left, b_left, W_right, b_right, W_ent, b_ent,
            left_child, right_child, qe_bf, ql_bf, qr_bf, qe8, ql8, qr8, out,
            ent_emb, rel_emb, entT8, entB8, relT8, relB8, NITEMS);
        flash11<<<dim3(512), dim3(256), 0, stream>>>(
            qe8, ql8, qr8, entB8, relB8, entT8, relT8,
            entL, relLL, relLR, entO, relOL, relOR);
        combine_all<<<dim3(256, 3), dim3(256), 0, stream>>>(
            entO, entL, relOL, relLL, relOR, relLR, out);
    } else if (ws_size >= WS_FALLBACK) {
        prep_conv<<<dim3(NPREPM + NCOPY), dim3(256), 0, stream>>>(
            query, W_left, b_left, W_right, b_right, W_ent, b_ent,
            left_child, right_child, qe_bf, ql_bf, qr_bf, qe8, ql8, qr8, out,
            ent_emb, rel_emb, (u8*)ws, (u8*)ws, (u8*)ws, (u8*)ws, 0);
        attend_simple<<<dim3(512), dim3(256), 0, stream>>>(qe_bf, ent_emb, ENT_N, out, 512, 393216);
        attend_simple<<<dim3(512), dim3(256), 0, stream>>>(ql_bf, rel_emb, REL_N, out, 256, -1);
        attend_simple<<<dim3(512), dim3(256), 0, stream>>>(qr_bf, rel_emb, REL_N, out, 393472, -1);
    }
    (void)in_sizes; (void)n_in; (void)out_size;
}

// Round 12
// 233.465 us; speedup vs baseline: 1.3637x; 1.0882x over previous
//
#include <hip/hip_runtime.h>
#include <hip/hip_bf16.h>
#include <math.h>

typedef __bf16 bf16;
typedef unsigned short u16;
typedef unsigned int u32;
typedef unsigned long long u64;
typedef long long i64;
typedef unsigned char u8;
typedef __attribute__((ext_vector_type(16))) float f32x16;
typedef __attribute__((ext_vector_type(8))) int i32x8;
typedef __attribute__((address_space(1))) void gvoid;
typedef __attribute__((address_space(3))) void svoid;

#define ENT_N 100000
#define REL_N 2000
#define ENT_CH 120        // partial chunks per qt (ent)
#define REL_CH 4          // partial chunks per (side,qt) (rel)

#define NPREPM 1536       // prep matmul blocks (128 rowgroups x 12 j-tiles)
#define NITEMS 6380       // conv items (1595 rowgroups x 4 e-chunks)
#define NCOPY  256        // passthrough copy blocks

static __device__ __forceinline__ i32x8 mk8(uint4 a, uint4 b) {
    i32x8 r;
    r[0] = (int)a.x; r[1] = (int)a.y; r[2] = (int)a.z; r[3] = (int)a.w;
    r[4] = (int)b.x; r[5] = (int)b.y; r[6] = (int)b.z; r[7] = (int)b.w;
    return r;
}

// ---------------------------------------------------------------------------
// prep projection tile (pipelined, verified R4): 64 out cols x 4 q-rows,
// W staged via 2-buffer LDS ping-pong, one barrier per 32-k chunk.
// ---------------------------------------------------------------------------
template<int KLEN>
static __device__ __forceinline__ void prep_tile(
    const float* __restrict__ query, const float* __restrict__ W,
    const float* __restrict__ bias, int b0, int rowbase, int qwoff,
    bf16* __restrict__ outBf, u8* __restrict__ out8, float* smem)
{
    const int t = threadIdx.x;
    float* qs = smem;               // [4][KLEN]
    float* Wl = smem + 4 * KLEN;    // 2 x [64][33]

#pragma unroll
    for (int i = 0; i < 4 * KLEN / 256; ++i) {
        const int l = t + 256 * i;
        const int r = l / KLEN, k = l % KLEN;
        qs[l] = query[(size_t)(b0 + r) * 768 + qwoff + k];
    }

    const int j = t & 63, r = t >> 6;
    const int srow = t >> 3, skq = t & 7;
    const float* wbase = W + (size_t)rowbase * KLEN;

    float4 v0, v1;
    auto wload = [&](int c) {
        v0 = *(const float4*)(wbase + (size_t)srow * KLEN + c * 32 + skq * 4);
        v1 = *(const float4*)(wbase + (size_t)(srow + 32) * KLEN + c * 32 + skq * 4);
    };
    auto wstore = [&](float* dst) {
        float* d0 = dst + srow * 33 + skq * 4;
        d0[0] = v0.x; d0[1] = v0.y; d0[2] = v0.z; d0[3] = v0.w;
        float* d1 = dst + (srow + 32) * 33 + skq * 4;
        d1[0] = v1.x; d1[1] = v1.y; d1[2] = v1.z; d1[3] = v1.w;
    };

    float acc = 0.f;
    wload(0);
    wstore(Wl);
    constexpr int NC = KLEN / 32;
    for (int c = 0; c < NC; ++c) {
        if (c + 1 < NC) wload(c + 1);
        __syncthreads();
        const float* wr = Wl + (c & 1) * 2112 + j * 33;
        const float* qr = qs + r * KLEN + c * 32;
#pragma unroll
        for (int k = 0; k < 32; ++k) acc += wr[k] * qr[k];
        if (c + 1 < NC) wstore(Wl + ((c + 1) & 1) * 2112);
    }
    acc += bias[rowbase + j];

    const size_t o = (size_t)(b0 + r) * 256 + rowbase + j;
    outBf[o] = (bf16)acc;
    out8[o] = (u8)__builtin_amdgcn_cvt_pk_fp8_f32(acc, acc, 0, false);
}

// ---------------------------------------------------------------------------
// prep_conv (R4 verbatim — best measured variant, 65.5 us):
//   blocks [0, NPREPM)             : projection tiles (pipelined)
//   blocks [NPREPM, NPREPM+nconv)  : conv items one-per-block
//   blocks [NPREPM+nconv, +NCOPY)  : passthrough copies
// ---------------------------------------------------------------------------
__global__ __launch_bounds__(256) void prep_conv(
    const float* __restrict__ query,
    const float* __restrict__ W_left, const float* __restrict__ b_left,
    const float* __restrict__ W_right, const float* __restrict__ b_right,
    const float* __restrict__ W_ent, const float* __restrict__ b_ent,
    const float* __restrict__ lc, const float* __restrict__ rc,
    bf16* __restrict__ qe, bf16* __restrict__ ql, bf16* __restrict__ qr,
    u8* __restrict__ qe8, u8* __restrict__ ql8, u8* __restrict__ qr8,
    float* __restrict__ out,
    const float* __restrict__ entF, const float* __restrict__ relF,
    u8* __restrict__ entT, u8* __restrict__ entB,
    u8* __restrict__ relT, u8* __restrict__ relB,
    int nconv)
{
    __shared__ float smem[7296];    // prep: 3072+4224; conv tile: 4160
    const int blk = blockIdx.x;
    const int t = threadIdx.x;

    if (blk < NPREPM) {
        const int rg = blk / 12, jt = blk % 12;
        const int b0 = rg * 4;
        const int proj = jt >> 2, rowbase = (jt & 3) * 64;
        if (proj == 0)
            prep_tile<768>(query, W_ent, b_ent, b0, rowbase, 0, qe, qe8, smem);
        else if (proj == 1)
            prep_tile<256>(query, W_left, b_left, b0, rowbase, 256, ql, ql8, smem);
        else
            prep_tile<256>(query, W_right, b_right, b0, rowbase, 256, qr, qr8, smem);
        return;
    }
    if (blk >= NPREPM + nconv) {
        const int idx = (blk - NPREPM - nconv) * 256 + t;
        if (idx < 32768) {
            const int q = idx >> 6, e4 = idx & 63;
            float4 v = *(const float4*)(lc + (size_t)q * 768 + e4 * 4);
            *(float4*)(out + (size_t)q * 768 + e4 * 4) = v;
        } else {
            const int j = idx - 32768;
            const int q = j >> 6, e4 = j & 63;
            float4 v = *(const float4*)(rc + (size_t)q * 768 + 512 + e4 * 4);
            *(float4*)(out + (size_t)393216 + q * 768 + 512 + e4 * 4) = v;
        }
        return;
    }

    // ---- conv: fp32 tables -> per-64-row-group fp8 MX blobs (16 KB each)
    //   K blob: [sub 2][kc 4][kb 2][n 32][32 B]
    //   V blob: [et 8][kb 2][n 32][j 32]  (rows permuted to MFMA C-layout)
    const int cidx = blk - NPREPM;
    const int x = cidx >> 2, y = cidx & 3;
    const float* in; u8* outT; u8* outB; int R; int g;
    if (x < 1563) {
        in = entF; outT = entT; outB = entB; R = ENT_N; g = x;
    } else {
        in = relF; outT = relT; outB = relB; R = REL_N; g = x - 1563;
    }
    const int r0 = g * 64;
    float* tile = smem;            // [64][65]
    const int e0 = y * 64;

    const int eg = t & 7, rowb = t >> 3;
#pragma unroll
    for (int item = 0; item < 2; ++item) {
        const int r = rowb + item * 32;
        float4 a, b;
        if ((r0 + r) < R) {
            const float* src = in + (size_t)(r0 + r) * 256 + e0 + eg * 8;
            a = *(const float4*)src;
            b = *(const float4*)(src + 4);
        } else { a = make_float4(0.f, 0.f, 0.f, 0.f); b = a; }
        float* dst = tile + r * 65 + eg * 8;
        dst[0] = a.x; dst[1] = a.y; dst[2] = a.z; dst[3] = a.w;
        dst[4] = b.x; dst[5] = b.y; dst[6] = b.z; dst[7] = b.w;
    }
    __syncthreads();

    // ---- K emit: kc = y, all 64 rows ----
    {
        const int n2 = t >> 2, piece = t & 3;
        const int sub = n2 >> 5, nn = n2 & 31;
        const int kbk = piece >> 1, jh = piece & 1;
        const float* src = tile + n2 * 65 + kbk * 32 + jh * 16;
        u32 xx; uint4 o;
        xx = __builtin_amdgcn_cvt_pk_fp8_f32(src[0], src[1], 0, false);
        o.x = __builtin_amdgcn_cvt_pk_fp8_f32(src[2], src[3], xx, true);
        xx = __builtin_amdgcn_cvt_pk_fp8_f32(src[4], src[5], 0, false);
        o.y = __builtin_amdgcn_cvt_pk_fp8_f32(src[6], src[7], xx, true);
        xx = __builtin_amdgcn_cvt_pk_fp8_f32(src[8], src[9], 0, false);
        o.z = __builtin_amdgcn_cvt_pk_fp8_f32(src[10], src[11], xx, true);
        xx = __builtin_amdgcn_cvt_pk_fp8_f32(src[12], src[13], 0, false);
        o.w = __builtin_amdgcn_cvt_pk_fp8_f32(src[14], src[15], xx, true);
        *(uint4*)(outB + (size_t)g * 16384 + sub * 8192 +
                  (size_t)y * 2048 + kbk * 1024 + nn * 32 + jh * 16) = o;
    }
    // ---- V emit: et = 2y, 2y+1, all 64 k-slots ----
    {
        const int etl = t >> 7, kbv = (t >> 6) & 1;
        const int nv = (t >> 1) & 31, jh = t & 1;
        const int colL = etl * 32 + nv;
        float v[16];
#pragma unroll
        for (int i = 0; i < 16; ++i) {
            const int row = jh * 32 + (i & 3) + 8 * (i >> 2) + 4 * kbv;
            v[i] = tile[row * 65 + colL];
        }
        u32 xx; uint4 o;
        xx = __builtin_amdgcn_cvt_pk_fp8_f32(v[0], v[1], 0, false);
        o.x = __builtin_amdgcn_cvt_pk_fp8_f32(v[2], v[3], xx, true);
        xx = __builtin_amdgcn_cvt_pk_fp8_f32(v[4], v[5], 0, false);
        o.y = __builtin_amdgcn_cvt_pk_fp8_f32(v[6], v[7], xx, true);
        xx = __builtin_amdgcn_cvt_pk_fp8_f32(v[8], v[9], 0, false);
        o.z = __builtin_amdgcn_cvt_pk_fp8_f32(v[10], v[11], xx, true);
        xx = __builtin_amdgcn_cvt_pk_fp8_f32(v[12], v[13], 0, false);
        o.w = __builtin_amdgcn_cvt_pk_fp8_f32(v[14], v[15], xx, true);
        *(uint4*)(outT + (size_t)g * 16384 +
                  (size_t)(y * 2 + etl) * 2048 +
                  kbv * 1024 + nv * 32 + jh * 16) = o;
    }
}

// ---------------------------------------------------------------------------
// flash12: flash10 (LDS dbuf staging — proven faster than direct-L2, R11)
// with COUNTED-vmcnt barriers (guide T4). flash10's __syncthreads compiled
// to `s_waitcnt vmcnt(0); s_barrier`, draining the just-issued k+1 prefetch
// every tile — serializing prefetch with compute (the documented ~20-40%
// m97-structure stall). Each wave issues exactly 8 global_load_lds per
// stage, so tile-k readiness needs only vmcnt(8) (tile k+1's 8 loads stay
// in flight across the barrier). Bottom barrier is a raw s_barrier (read-
// completion fence only; ds_read results are consumed by MFMAs before it).
// Buffer-overwrite safety unchanged: iter k+1 writes buf k&1 only after
// iter k's bottom barrier.
// ---------------------------------------------------------------------------
__global__ __launch_bounds__(256, 2) void flash12(
    const u8* __restrict__ qeP, const u8* __restrict__ qlP,
    const u8* __restrict__ qrP,
    const u8* __restrict__ entB, const u8* __restrict__ relB,
    const u8* __restrict__ entT, const u8* __restrict__ relT,
    float* __restrict__ entL, float* __restrict__ relLL,
    float* __restrict__ relLR,
    u16* __restrict__ entO, u16* __restrict__ relOL, u16* __restrict__ relOR)
{
    const int tid = threadIdx.x;
    const int w = tid >> 6;
    const int lane = tid & 63;
    const int n = lane & 31;
    const int kb = lane >> 5;

    int qt, c, stride, nt, Nrows;
    const u8* qbf; const u8* tabB; const u8* tabT;
    float* pL; u16* pO;
    {
        const int id = blockIdx.x;
        if (id < 480) {
            qt = id / 120; c = id % 120;
            stride = 120; nt = (c < 3) ? 14 : 13;   // 1563 rowgroups
            Nrows = ENT_N;
            qbf = qeP; tabB = entB; tabT = entT; pL = entL; pO = entO;
        } else {
            const int r = id - 480;
            qt = (r >> 2) & 3; c = r & 3;
            stride = 4; nt = 8;                      // 32 rowgroups
            Nrows = REL_N;
            tabB = relB; tabT = relT;
            if (r < 16) { qbf = qlP; pL = relLL; pO = relOL; }
            else        { qbf = qrP; pL = relLR; pO = relOR; }
        }
    }
    const int q0 = qt * 128;
    const int qw = q0 + w * 32;

    __shared__ __align__(16) u8 lds[65536];
    u16* lds16 = (u16*)lds;

    const u8* qrow = qbf + (size_t)(qw + n) * 256;
    i32x8 qf[4];
#pragma unroll
    for (int kc = 0; kc < 4; ++kc) {
        uint4 a = *(const uint4*)(qrow + kc * 64 + kb * 32);
        uint4 b = *(const uint4*)(qrow + kc * 64 + kb * 32 + 16);
        qf[kc] = mk8(a, b);
    }

    f32x16 acc[8];
#pragma unroll
    for (int et = 0; et < 8; ++et)
#pragma unroll
        for (int i = 0; i < 16; ++i) acc[et][i] = 0.f;
    float l_run = 0.f;

    auto stage = [&](int buf, int g) {
        u8* sK = lds + buf * 32768;
        u8* sV = sK + 16384;
        const u8* ksrc = tabB + (size_t)g * 16384 + w * 4096 + (size_t)lane * 16;
        const u8* vsrc = tabT + (size_t)g * 16384 + w * 4096 + (size_t)lane * 16;
#pragma unroll
        for (int o = 0; o < 4096; o += 1024) {
            __builtin_amdgcn_global_load_lds((gvoid*)(ksrc + o),
                                             (svoid*)(sK + w * 4096 + o), 16, 0, 0);
            __builtin_amdgcn_global_load_lds((gvoid*)(vsrc + o),
                                             (svoid*)(sV + w * 4096 + o), 16, 0, 0);
        }
    };

    int rt = c;
    stage(0, rt);                       // 8 loads/wave outstanding (tile 0)

    for (int k = 0; k < nt; ++k) {
        if (k + 1 < nt) {
            stage((k + 1) & 1, rt + stride);            // +8 (tile k+1)
            asm volatile("s_waitcnt vmcnt(8)" ::: "memory");  // tile k done
        } else {
            asm volatile("s_waitcnt vmcnt(0)" ::: "memory");
        }
        __builtin_amdgcn_s_barrier();   // buf k&1 ready for all waves

        const u8* sK = lds + (k & 1) * 32768;
        const u8* sV = sK + 16384;
        const int gr = rt * 64;

        // ---- logits^T for two 32-row subtiles ----
        f32x16 L0, L1;
#pragma unroll
        for (int i = 0; i < 16; ++i) { L0[i] = 0.f; L1[i] = 0.f; }
        const u8* kbase = sK + kb * 1024 + n * 32;
#pragma unroll
        for (int kc = 0; kc < 4; ++kc) {
            uint4 a0 = *(const uint4*)(kbase + kc * 2048);
            uint4 a1 = *(const uint4*)(kbase + kc * 2048 + 16);
            L0 = __builtin_amdgcn_mfma_scale_f32_32x32x64_f8f6f4(
                mk8(a0, a1), qf[kc], L0, 0, 0, 0, 0x7f7f7f7f, 0, 0x7f7f7f7f);
            uint4 b0 = *(const uint4*)(kbase + 8192 + kc * 2048);
            uint4 b1 = *(const uint4*)(kbase + 8192 + kc * 2048 + 16);
            L1 = __builtin_amdgcn_mfma_scale_f32_32x32x64_f8f6f4(
                mk8(b0, b1), qf[kc], L1, 0, 0, 0, 0x7f7f7f7f, 0, 0x7f7f7f7f);
        }
        if (gr + 64 > Nrows) {
#pragma unroll
            for (int r = 0; r < 16; ++r) {
                const int row = (r & 3) + 8 * (r >> 2) + 4 * kb;
                if (gr + row >= Nrows)      L0[r] = -1e30f;
                if (gr + 32 + row >= Nrows) L1[r] = -1e30f;
            }
        }
        // ---- P = exp(L), row-sum ----
        float rs = 0.f;
#pragma unroll
        for (int r = 0; r < 16; ++r) {
            const float p0 = __expf(L0[r]); L0[r] = p0; rs += p0;
            const float p1 = __expf(L1[r]); L1[r] = p1; rs += p1;
        }
        rs += __shfl_xor(rs, 32);
        l_run += rs;
        // ---- P -> fp8 B-fragment (register order; V permutation matches) ----
        u32 p[8];
#pragma unroll
        for (int i = 0; i < 4; ++i) {
            u32 x = __builtin_amdgcn_cvt_pk_fp8_f32(L0[i * 4 + 0], L0[i * 4 + 1], 0, false);
            p[i] = __builtin_amdgcn_cvt_pk_fp8_f32(L0[i * 4 + 2], L0[i * 4 + 3], x, true);
            u32 y = __builtin_amdgcn_cvt_pk_fp8_f32(L1[i * 4 + 0], L1[i * 4 + 1], 0, false);
            p[i + 4] = __builtin_amdgcn_cvt_pk_fp8_f32(L1[i * 4 + 2], L1[i * 4 + 3], y, true);
        }
        uint4 pa; pa.x = p[0]; pa.y = p[1]; pa.z = p[2]; pa.w = p[3];
        uint4 pb; pb.x = p[4]; pb.y = p[5]; pb.z = p[6]; pb.w = p[7];
        const i32x8 bv = mk8(pa, pb);
        // ---- PV: O^T += V^T x P ----
        const u8* vbase = sV + kb * 1024 + n * 32;
#pragma unroll
        for (int et = 0; et < 8; ++et) {
            uint4 v0 = *(const uint4*)(vbase + et * 2048);
            uint4 v1 = *(const uint4*)(vbase + et * 2048 + 16);
            acc[et] = __builtin_amdgcn_mfma_scale_f32_32x32x64_f8f6f4(
                mk8(v0, v1), bv, acc[et], 0, 0, 0, 0x7f7f7f7f, 0, 0x7f7f7f7f);
        }
        rt += stride;
        __builtin_amdgcn_s_barrier();   // all waves done reading buf k&1
    }

    if (lane < 32) pL[(size_t)c * 512 + qw + n] = l_run;

    // ---- write partial O via LDS transpose (stride 264, two wave-pairs) ----
    for (int half = 0; half < 2; ++half) {
        __syncthreads();
        if ((w >> 1) == half) {
            u16* rgn = lds16 + (w & 1) * 8448;   // [32 q][264]
#pragma unroll
            for (int et = 0; et < 8; ++et)
#pragma unroll
                for (int a2 = 0; a2 < 4; ++a2) {
                    bf16 h0 = (bf16)acc[et][a2 * 4 + 0];
                    bf16 h1 = (bf16)acc[et][a2 * 4 + 1];
                    bf16 h2 = (bf16)acc[et][a2 * 4 + 2];
                    bf16 h3 = (bf16)acc[et][a2 * 4 + 3];
                    uint2 pk;
                    pk.x = ((u32)(*(u16*)&h1) << 16) | (u32)(*(u16*)&h0);
                    pk.y = ((u32)(*(u16*)&h3) << 16) | (u32)(*(u16*)&h2);
                    *(uint2*)(rgn + n * 264 + et * 32 + 8 * a2 + 4 * kb) = pk;
                }
        }
        __syncthreads();
#pragma unroll
        for (int rg = 0; rg < 2; ++rg) {
            const int qt2 = q0 + (half * 2 + rg) * 32;
            const u16* src = lds16 + rg * 8448;
            const int qq = tid >> 3, e0 = (tid & 7) * 32;
#pragma unroll
            for (int i = 0; i < 4; ++i) {
                const u16* sp = src + qq * 264 + e0 + i * 8;
                uint2 a = *(const uint2*)(sp);
                uint2 b = *(const uint2*)(sp + 4);
                uint4 wv; wv.x = a.x; wv.y = a.y; wv.z = b.x; wv.w = b.y;
                *(uint4*)(pO + ((size_t)c * 512 + qt2 + qq) * 256 + e0 + i * 8) = wv;
            }
        }
    }
}

// ---------------------------------------------------------------------------
// combine_all v2: grid (256, 3): y=0 ent (CH=120), y=1 relL, y=2 relR (CH=4).
// Block = 2 q; thread = (qi, e-group, c-segment of CH/4). l-sum fused,
// 4-way c-split shortens the load chain, LDS-reduce across segments.
// ---------------------------------------------------------------------------
__global__ __launch_bounds__(256) void combine_all(
    const u16* __restrict__ entO, const float* __restrict__ entL,
    const u16* __restrict__ relOL, const float* __restrict__ relLL,
    const u16* __restrict__ relOR, const float* __restrict__ relLR,
    float* __restrict__ out)
{
    const u16* pO; const float* pl; int CH, baseA, baseB;
    if (blockIdx.y == 0) { pO = entO; pl = entL; CH = ENT_CH; baseA = 512; baseB = 393216; }
    else if (blockIdx.y == 1) { pO = relOL; pl = relLL; CH = REL_CH; baseA = 256; baseB = -1; }
    else { pO = relOR; pl = relLR; CH = REL_CH; baseA = 393472; baseB = -1; }

    const int t = threadIdx.x;
    const int qi = t >> 7;            // 0..1
    const int e0g = (t >> 2) & 31;    // 0..31
    const int seg = t & 3;            // 0..3
    const int q = blockIdx.x * 2 + qi;
    const int e0 = e0g * 8;
    const int cnt = CH >> 2;
    const int cbeg = seg * cnt;

    float s = 0.f;
    float a[8];
#pragma unroll
    for (int k = 0; k < 8; ++k) a[k] = 0.f;
#pragma unroll 6
    for (int c = cbeg; c < cbeg + cnt; ++c) {
        s += pl[(size_t)c * 512 + q];
        const uint4 wv = *(const uint4*)(pO + ((size_t)c * 512 + q) * 256 + e0);
        const u32 ww[4] = {wv.x, wv.y, wv.z, wv.w};
#pragma unroll
        for (int p = 0; p < 4; ++p) {
            a[p * 2]     += __uint_as_float((ww[p] & 0xffffu) << 16);
            a[p * 2 + 1] += __uint_as_float(ww[p] & 0xffff0000u);
        }
    }

    __shared__ float red[2][32][4][11];   // pad 11: conflict-free writes
    float* slot = red[qi][e0g][seg];
#pragma unroll
    for (int k = 0; k < 8; ++k) slot[k] = a[k];
    slot[8] = s;
    __syncthreads();
    if (seg == 0) {
        float st = 0.f;
        float b[8];
#pragma unroll
        for (int k = 0; k < 8; ++k) b[k] = 0.f;
#pragma unroll
        for (int sgi = 0; sgi < 4; ++sgi) {
            const float* sl = red[qi][e0g][sgi];
            st += sl[8];
#pragma unroll
            for (int k = 0; k < 8; ++k) b[k] += sl[k];
        }
        const float inv = 1.f / st;
#pragma unroll
        for (int k = 0; k < 8; ++k) b[k] *= inv;
        float4 o1 = {b[0], b[1], b[2], b[3]};
        float4 o2 = {b[4], b[5], b[6], b[7]};
        *(float4*)(out + (size_t)baseA + (size_t)q * 768 + e0) = o1;
        *(float4*)(out + (size_t)baseA + (size_t)q * 768 + e0 + 4) = o2;
        if (baseB >= 0) {
            *(float4*)(out + (size_t)baseB + (size_t)q * 768 + e0) = o1;
            *(float4*)(out + (size_t)baseB + (size_t)q * 768 + e0 + 4) = o2;
        }
    }
}

// ---------------------------------------------------------------------------
// Fallback (small ws): fp32 online-softmax attend, bf16 q input.
// ---------------------------------------------------------------------------
__global__ __launch_bounds__(256) void attend_simple(
    const bf16* __restrict__ qbf, const float* __restrict__ tab, int Nrows,
    float* __restrict__ out, int baseA, int baseB)
{
    const int q = blockIdx.x;
    const int t = threadIdx.x, wave = t >> 6, lane = t & 63;
    float qv[4];
#pragma unroll
    for (int i = 0; i < 4; ++i) qv[i] = (float)qbf[(size_t)q * 256 + lane + 64 * i];
    float m = -INFINITY, l = 0.f, o[4] = {0.f, 0.f, 0.f, 0.f};
    for (int r = wave; r < Nrows; r += 4) {
        const float* row = tab + (size_t)r * 256;
        float d = 0.f;
#pragma unroll
        for (int i = 0; i < 4; ++i) d += qv[i] * row[lane + 64 * i];
#pragma unroll
        for (int s = 32; s; s >>= 1) d += __shfl_xor(d, s);
        const float mn = fmaxf(m, d);
        const float al = __expf(m - mn);
        const float p = __expf(d - mn);
#pragma unroll
        for (int i = 0; i < 4; ++i) o[i] = o[i] * al + p * row[lane + 64 * i];
        l = l * al + p; m = mn;
    }
    __shared__ float sm[4], sl[4], so[4][256];
    if (lane == 0) { sm[wave] = m; sl[wave] = l; }
#pragma unroll
    for (int i = 0; i < 4; ++i) so[wave][lane + 64 * i] = o[i];
    __syncthreads();
    const float M = fmaxf(fmaxf(sm[0], sm[1]), fmaxf(sm[2], sm[3]));
    const float w0 = __expf(sm[0] - M), w1 = __expf(sm[1] - M);
    const float w2 = __expf(sm[2] - M), w3 = __expf(sm[3] - M);
    const float L = w0 * sl[0] + w1 * sl[1] + w2 * sl[2] + w3 * sl[3];
    const float a = (w0 * so[0][t] + w1 * so[1][t] + w2 * so[2][t] + w3 * so[3][t]) / L;
    out[(size_t)baseA + (size_t)q * 768 + t] = a;
    if (baseB >= 0) out[(size_t)baseB + (size_t)q * 768 + t] = a;
}

// ---------------------------------------------------------------------------
extern "C" void kernel_launch(void* const* d_in, const int* in_sizes, int n_in,
                              void* d_out, int out_size, void* d_ws, size_t ws_size,
                              hipStream_t stream)
{
    const float* left_child  = (const float*)d_in[0];
    const float* right_child = (const float*)d_in[1];
    const float* query       = (const float*)d_in[2];
    const float* ent_emb     = (const float*)d_in[3];
    const float* rel_emb     = (const float*)d_in[4];
    const float* W_left      = (const float*)d_in[5];
    const float* b_left      = (const float*)d_in[6];
    const float* W_right     = (const float*)d_in[7];
    const float* b_right     = (const float*)d_in[8];
    const float* W_ent       = (const float*)d_in[9];
    const float* b_ent       = (const float*)d_in[10];
    float* out = (float*)d_out;
    char* ws = (char*)d_ws;

    // ws layout (bytes)
    bf16* qe_bf = (bf16*)(ws + 0);            //    262,144 (fallback)
    bf16* ql_bf = (bf16*)(ws + 262144);       //    262,144
    bf16* qr_bf = (bf16*)(ws + 524288);       //    262,144
    u8*   qe8   = (u8*)(ws + 786432);         //    131,072
    u8*   ql8   = (u8*)(ws + 917504);         //    131,072
    u8*   qr8   = (u8*)(ws + 1048576);        //    131,072
    u8*   entT8 = (u8*)(ws + 1179648);        // 25,608,192 (1563 grp x 16 KB)
    u8*   relT8 = (u8*)(ws + 26787840);       //    524,288 (32 grp x 16 KB)
    u8*   entB8 = (u8*)(ws + 27312128);       // 25,608,192
    u8*   relB8 = (u8*)(ws + 52920320);       //    524,288
    float* entL = (float*)(ws + 53444608);    //    245,760 (120*512*4)
    u16*  entO  = (u16*)(ws + 53690368);      // 31,457,280 (120*512*256*2)
    float* relLL = (float*)(ws + 85147648);   //      8,192
    float* relLR = (float*)(ws + 85155840);   //      8,192
    u16*  relOL = (u16*)(ws + 85164032);      //  1,048,576
    u16*  relOR = (u16*)(ws + 86212608);      //  1,048,576
    const size_t WS_FULL = 87261184;
    const size_t WS_FALLBACK = 786432;

    if (ws_size >= WS_FULL) {
        prep_conv<<<dim3(NPREPM + NITEMS + NCOPY), dim3(256), 0, stream>>>(
            query, W_left, b_left, W_right, b_right, W_ent, b_ent,
            left_child, right_child, qe_bf, ql_bf, qr_bf, qe8, ql8, qr8, out,
            ent_emb, rel_emb, entT8, entB8, relT8, relB8, NITEMS);
        flash12<<<dim3(512), dim3(256), 0, stream>>>(
            qe8, ql8, qr8, entB8, relB8, entT8, relT8,
            entL, relLL, relLR, entO, relOL, relOR);
        combine_all<<<dim3(256, 3), dim3(256), 0, stream>>>(
            entO, entL, relOL, relLL, relOR, relLR, out);
    } else if (ws_size >= WS_FALLBACK) {
        prep_conv<<<dim3(NPREPM + NCOPY), dim3(256), 0, stream>>>(
            query, W_left, b_left, W_right, b_right, W_ent, b_ent,
            left_child, right_child, qe_bf, ql_bf, qr_bf, qe8, ql8, qr8, out,
            ent_emb, rel_emb, (u8*)ws, (u8*)ws, (u8*)ws, (u8*)ws, 0);
        attend_simple<<<dim3(512), dim3(256), 0, stream>>>(qe_bf, ent_emb, ENT_N, out, 512, 393216);
        attend_simple<<<dim3(512), dim3(256), 0, stream>>>(ql_bf, rel_emb, REL_N, out, 256, -1);
        attend_simple<<<dim3(512), dim3(256), 0, stream>>>(qr_bf, rel_emb, REL_N, out, 393472, -1);
    }
    (void)in_sizes; (void)n_in; (void)out_size;
}